// Round 3
// baseline (582.802 us; speedup 1.0000x reference)
//
#include <hip/hip_runtime.h>
#include <math.h>

typedef unsigned short ushort_t;
typedef __attribute__((ext_vector_type(8))) short short8;   // 8 bf16 = 4 VGPRs
typedef __attribute__((ext_vector_type(4))) float floatx4;  // MFMA accumulator

// Problem constants
constexpr int NT = 4096;     // tokens
constexpr int H  = 1024;     // hidden
constexpr int V  = 50257;    // vocab
constexpr int CUT1 = 20000;
constexpr int CUT2 = 40000;

// MFMA-path geometry (256x256 tile, BK=32, 4-deep ring)
constexpr int NPAD_TOK = 4352;            // 4096 + 256 pad rows (zeroed)
constexpr int NPAD_COL = 50560;           // covers 50240+256
constexpr int CT0 = 79, CT1 = 79, CT2 = 41;    // 256-wide col tiles
constexpr int CT_TOTAL = CT0 + CT1 + CT2;      // 199
constexpr int MAX_TTILES = 16;                 // 4096/256 worst case
constexpr int CT_GROUPS = (CT_TOTAL + 7) / 8;  // 25 per XCD
constexpr int MFMA_GRID = 8 * CT_GROUPS * MAX_TTILES;  // 3200 blocks
constexpr int NKT = H / 32;                    // 32 K-tiles of BK=32

// fp32 fallback geometry (round-1 path, used only if ws too small)
constexpr int FB_TILES0 = (20000 + 63) / 64;
constexpr int FB_TILES1 = (20000 + 63) / 64;
constexpr int FB_TILES2 = (V - 40000 + 63) / 64;
constexpr int FB_TOTAL = FB_TILES0 + FB_TILES1 + FB_TILES2;

__device__ __forceinline__ ushort_t f2bf(float f) {
  unsigned int u = __float_as_uint(f);
  u = (u + 0x7FFFu + ((u >> 16) & 1u)) >> 16;  // round-to-nearest-even
  return (ushort_t)u;
}
__device__ __forceinline__ float bf2f(ushort_t b) {
  return __uint_as_float(((unsigned int)b) << 16);
}
__device__ __forceinline__ void gl_lds16(const void* g, void* l) {
  __builtin_amdgcn_global_load_lds(
      (const __attribute__((address_space(1))) void*)g,
      (__attribute__((address_space(3))) void*)l, 16, 0, 0);
}

// ---------------------------------------------------------------------------
// Kernel 1: classify tokens, build perm (ballot + exact prefix, atomic-free,
// deterministic), zero sumexp.
// ---------------------------------------------------------------------------
__global__ __launch_bounds__(1024) void setup_kernel(
    const int* __restrict__ y, int* __restrict__ offsets,
    int* __restrict__ perm, float* __restrict__ sumexp) {
  __shared__ int wcnt[16][3];
  __shared__ int wstart[16][3];
  int tid = threadIdx.x, lane = tid & 63, wid = tid >> 6;
  for (int i = tid; i < NT; i += 1024) sumexp[i] = 0.f;

  int kc[4];
  unsigned long long msk[4][3];
  int cw0 = 0, cw1 = 0, cw2 = 0;
  #pragma unroll
  for (int e = 0; e < 4; e++) {
    int v = y[tid + e * 1024];
    kc[e] = (v >= CUT1) + (v >= CUT2);
    msk[e][0] = __ballot(kc[e] == 0);
    msk[e][1] = __ballot(kc[e] == 1);
    msk[e][2] = __ballot(kc[e] == 2);
    cw0 += __popcll(msk[e][0]);
    cw1 += __popcll(msk[e][1]);
    cw2 += __popcll(msk[e][2]);
  }
  if (lane == 0) { wcnt[wid][0] = cw0; wcnt[wid][1] = cw1; wcnt[wid][2] = cw2; }
  __syncthreads();
  if (tid == 0) {
    int t0 = 0, t1 = 0, t2 = 0;
    for (int wv = 0; wv < 16; wv++) { t0 += wcnt[wv][0]; t1 += wcnt[wv][1]; t2 += wcnt[wv][2]; }
    offsets[0] = 0; offsets[1] = t0; offsets[2] = t0 + t1; offsets[3] = NT;
    int c0 = 0, c1 = t0, c2 = t0 + t1;
    for (int wv = 0; wv < 16; wv++) {
      wstart[wv][0] = c0; c0 += wcnt[wv][0];
      wstart[wv][1] = c1; c1 += wcnt[wv][1];
      wstart[wv][2] = c2; c2 += wcnt[wv][2];
    }
  }
  __syncthreads();
  int r0 = wstart[wid][0], r1 = wstart[wid][1], r2 = wstart[wid][2];
  unsigned long long below = (1ull << lane) - 1ull;
  #pragma unroll
  for (int e = 0; e < 4; e++) {
    int t = tid + e * 1024;
    int c = kc[e];
    int start = (c == 0) ? r0 : ((c == 1) ? r1 : r2);
    perm[start + __popcll(msk[e][c] & below)] = t;
    r0 += __popcll(msk[e][0]);
    r1 += __popcll(msk[e][1]);
    r2 += __popcll(msk[e][2]);
  }
}

// ---------------------------------------------------------------------------
// Kernel 2: gather x into perm order as bf16 (float4 -> ushort4); zero pad.
// ---------------------------------------------------------------------------
__global__ __launch_bounds__(256) void gather_kernel(
    const float* __restrict__ x, const int* __restrict__ perm,
    ushort_t* __restrict__ xb) {
  int p = blockIdx.x;
  int src = (p < NT) ? perm[p] : -1;
  int k = threadIdx.x * 4;
  ushort4 o;
  if (src >= 0) {
    float4 v = *(const float4*)&x[(size_t)src * H + k];
    o.x = f2bf(v.x); o.y = f2bf(v.y); o.z = f2bf(v.z); o.w = f2bf(v.w);
  } else {
    o.x = 0; o.y = 0; o.z = 0; o.w = 0;
  }
  *(ushort4*)&xb[(size_t)p * H + k] = o;
}

// ---------------------------------------------------------------------------
// Kernel 3: transpose+convert logits [H][V] fp32 -> lt [NPAD_COL][H] bf16.
// ---------------------------------------------------------------------------
__global__ __launch_bounds__(256) void transpose_kernel(
    const float* __restrict__ logits, ushort_t* __restrict__ lt) {
  __shared__ float ts[64][129];
  int col0 = blockIdx.x * 128, k0 = blockIdx.y * 64;
  int tid = threadIdx.x;
  #pragma unroll
  for (int e = 0; e < 8; e++) {
    int i = e * 256 + tid;       // 0..2047
    int r = i >> 5, q = i & 31;  // row 0..63, float4-slot 0..31
    int col = col0 + q * 4;
    float4 v;
    if (col + 3 < V) {
      v = *(const float4*)&logits[(size_t)(k0 + r) * V + col];
    } else {
      v.x = (col + 0 < V) ? logits[(size_t)(k0 + r) * V + col + 0] : 0.f;
      v.y = (col + 1 < V) ? logits[(size_t)(k0 + r) * V + col + 1] : 0.f;
      v.z = (col + 2 < V) ? logits[(size_t)(k0 + r) * V + col + 2] : 0.f;
      v.w = (col + 3 < V) ? logits[(size_t)(k0 + r) * V + col + 3] : 0.f;
    }
    ts[r][4 * q + 0] = v.x;
    ts[r][4 * q + 1] = v.y;
    ts[r][4 * q + 2] = v.z;
    ts[r][4 * q + 3] = v.w;
  }
  __syncthreads();
  #pragma unroll
  for (int e = 0; e < 4; e++) {
    int i = e * 256 + tid;          // 0..1023
    int col = i >> 3, kq8 = i & 7;  // col 0..127, 8-k group 0..7
    short8 o;
    #pragma unroll
    for (int d = 0; d < 8; d++) o[d] = (short)f2bf(ts[8 * kq8 + d][col]);
    *(short8*)&lt[(size_t)(col0 + col) * H + k0 + 8 * kq8] = o;
  }
}

// ---------------------------------------------------------------------------
// Kernel 4: cluster-head log-softmax (fp32) + target logit (bf16 lt row).
// ---------------------------------------------------------------------------
__global__ __launch_bounds__(256) void head_kernel(
    const float* __restrict__ x, const int* __restrict__ y,
    const float* __restrict__ Wc, const ushort_t* __restrict__ lt,
    float* __restrict__ neg_cll, float* __restrict__ z_tgt) {
  int tid = threadIdx.x;
  int lane = tid & 63;
  int token = blockIdx.x * 4 + (tid >> 6);
  int yv = y[token];
  const float* xp = x + (size_t)token * H;
  const ushort_t* lp = lt + (size_t)yv * H;
  float c0 = 0.f, c1 = 0.f, c2 = 0.f, zt = 0.f;
  #pragma unroll
  for (int j = 0; j < 16; j++) {
    int h = lane + j * 64;
    float xv = xp[h];
    c0 = fmaf(xv, Wc[h], c0);
    c1 = fmaf(xv, Wc[H + h], c1);
    c2 = fmaf(xv, Wc[2 * H + h], c2);
    zt = fmaf(xv, bf2f(lp[h]), zt);
  }
  #pragma unroll
  for (int d = 32; d; d >>= 1) {
    c0 += __shfl_down(c0, d);
    c1 += __shfl_down(c1, d);
    c2 += __shfl_down(c2, d);
    zt += __shfl_down(zt, d);
  }
  if (lane == 0) {
    float m = fmaxf(c0, fmaxf(c1, c2));
    float lse = m + logf(expf(c0 - m) + expf(c1 - m) + expf(c2 - m));
    int k = (yv >= CUT1) + (yv >= CUT2);
    float ck = (k == 0) ? c0 : ((k == 1) ? c1 : c2);
    neg_cll[token] = lse - ck;
    z_tgt[token] = zt;
  }
}

// ---------------------------------------------------------------------------
// Kernel 5: MFMA main loop — 256x256 tile, BK=32, 4-deep K-tile ring buffer.
// 512 threads = 8 waves (2M x 4N), per-wave output 128x64 (8x4 fragments).
// Ring: stage K-tile k+3 while computing k -> issue-to-use ~3 K-tiles covers
// L3 latency (xb is 8.6 MB > per-XCD L2). ONE barrier per K-tile; counted
// vmcnt(8) steady-state (4 loads/wave/K-tile, 2 future tiles in flight),
// peeled 4/0 for the last K-tiles. LDS: K-tile rows are 64 B; two matrix
// rows per 128 B LDS row; 16B-chunk slot = quad ^ ((m>>1)&3) -> exact 2-way
// per 16-lane phase = conflict-free. Write-side inverse swizzle verified as
// an involution (both-sides-or-neither discipline, rule 21).
// ---------------------------------------------------------------------------
__global__ __launch_bounds__(512, 2) void mfma_kernel(
    const ushort_t* __restrict__ xb, const ushort_t* __restrict__ lt,
    const int* __restrict__ offsets, float* __restrict__ sumexp) {
  // XCD-aware decode: xcd = id%8 handles cts {xcd, xcd+8, ...}
  int id = blockIdx.x;
  int xcd = id & 7;
  int j = id >> 3;
  int ct = xcd + 8 * (j >> 4);   // ct-group per XCD
  int tt = j & 15;               // token tile within ct
  if (ct >= CT_TOTAL) return;

  int c, col0, colEnd;
  if (ct < CT0)            { c = 0; col0 = ct * 256;                      colEnd = CUT1; }
  else if (ct < CT0 + CT1) { c = 1; col0 = CUT1 + (ct - CT0) * 256;       colEnd = CUT2; }
  else                     { c = 2; col0 = CUT2 + (ct - CT0 - CT1) * 256; colEnd = V; }

  int t0 = offsets[c] + tt * 256;
  int tEnd = offsets[c + 1];
  if (t0 >= tEnd) return;  // uniform across block: no barrier divergence

  // 4 ring buffers x (A 16KB + B 16KB) = 128 KB LDS
  __shared__ __align__(16) ushort_t As[4][128 * 64];  // [buf][ldsrow][64] (2 mrows/ldsrow)
  __shared__ __align__(16) ushort_t Bs[4][128 * 64];

  int tid = threadIdx.x;
  int lane = tid & 63;
  int w = tid >> 6;                 // wave 0..7
  int wm = w >> 2, wn = w & 3;      // 2x4 wave grid
  int m_in = lane & 15, quad = lane >> 4;

  // ---- staging map: per wave per K-tile: 2 A + 2 B gl_lds (1 KB each).
  // instr cc covers LDS rows w*16+cc*8 .. +8. HW dst: base + lane*16.
  // lane: ldsrow lr = base+(lane>>3), slot ls = lane&7. Source: matrix row
  // m = 2*lr + (ls>>2), chunk q = (ls&3) ^ (lr&3) (inverse of read swizzle).
  const ushort_t* gA[2];
  const ushort_t* gB[2];
  #pragma unroll
  for (int cc = 0; cc < 2; cc++) {
    int lr = w * 16 + cc * 8 + (lane >> 3);
    int ls = lane & 7;
    int m  = 2 * lr + (ls >> 2);
    int q  = (ls & 3) ^ (lr & 3);
    gA[cc] = xb + (size_t)(t0 + m) * H + q * 8;
    gB[cc] = lt + (size_t)(col0 + m) * H + q * 8;
  }
  int ks = 0;  // next K-tile to stage
  auto STAGE = [&]() {
    int b = ks & 3;
    #pragma unroll
    for (int cc = 0; cc < 2; cc++) {
      gl_lds16(gA[cc], &As[b][(w * 16 + cc * 8) * 64]);
      gl_lds16(gB[cc], &Bs[b][(w * 16 + cc * 8) * 64]);
      gA[cc] += 32; gB[cc] += 32;  // advance one K-tile (32 elements)
    }
    ++ks;
  };

  // ---- read-side addressing (element offsets within a buf):
  // A frag i: matrix row = wm*128 + i*16 + m_in; lr = row>>1; h = row&1;
  // elem off = lr*64 + h*32 + (quad ^ (lr&3))*8; (lr&3) == ((m_in>>1)&3)
  // since wm*64 and i*8 are 0 mod 4.
  int sxor = quad ^ ((m_in >> 1) & 3);
  int aoff = (wm * 64 + (m_in >> 1)) * 64 + (m_in & 1) * 32 + sxor * 8;  // + i*512
  int boff = (wn * 32 + (m_in >> 1)) * 64 + (m_in & 1) * 32 + sxor * 8;  // + j*512

  floatx4 acc[8][4];
  #pragma unroll
  for (int i = 0; i < 8; i++)
    #pragma unroll
    for (int jj = 0; jj < 4; jj++)
      acc[i][jj] = (floatx4){0.f, 0.f, 0.f, 0.f};

  // ---- prologue: stage K-tiles 0,1,2; ensure tile 0 landed everywhere.
  STAGE(); STAGE(); STAGE();
  asm volatile("s_waitcnt vmcnt(8)" ::: "memory");
  __builtin_amdgcn_sched_barrier(0);
  __builtin_amdgcn_s_barrier();
  __builtin_amdgcn_sched_barrier(0);

  // ---- main loop: one barrier per K-tile; counted waits (never 0 mid-loop).
  #pragma unroll 4
  for (int k = 0; k < NKT; ++k) {
    int b = k & 3;
    const ushort_t* Ab = &As[b][0];
    const ushort_t* Bb = &Bs[b][0];

    if (k + 3 < NKT) STAGE();  // ring: writes buf (k+3)&3 = (k-1)&3, freed by
                               // the end-of-(k-1) barrier.
    __builtin_amdgcn_sched_barrier(0);  // pin prefetch issue ahead of compute

    short8 af[4], bf[4];
    #pragma unroll
    for (int i = 0; i < 4; i++) af[i] = *(const short8*)&Ab[aoff + i * 512];
    #pragma unroll
    for (int jj = 0; jj < 4; jj++) bf[jj] = *(const short8*)&Bb[boff + jj * 512];

    __builtin_amdgcn_s_setprio(1);
    #pragma unroll
    for (int i = 0; i < 4; i++)
      #pragma unroll
      for (int jj = 0; jj < 4; jj++)
        acc[i][jj] = __builtin_amdgcn_mfma_f32_16x16x32_bf16(af[i], bf[jj], acc[i][jj], 0, 0, 0);
    __builtin_amdgcn_s_setprio(0);

    #pragma unroll
    for (int i = 0; i < 4; i++) af[i] = *(const short8*)&Ab[aoff + (i + 4) * 512];

    __builtin_amdgcn_s_setprio(1);
    #pragma unroll
    for (int i = 0; i < 4; i++)
      #pragma unroll
      for (int jj = 0; jj < 4; jj++)
        acc[i + 4][jj] = __builtin_amdgcn_mfma_f32_16x16x32_bf16(af[i], bf[jj], acc[i + 4][jj], 0, 0, 0);
    __builtin_amdgcn_s_setprio(0);

    // end-of-K-tile: ensure tile k+1 landed (all waves), free buf b.
    if (k < NKT - 1) {
      if (k < NKT - 3) {
        asm volatile("s_waitcnt vmcnt(8)" ::: "memory");   // keep k+2,k+3 in flight
      } else if (k == NKT - 3) {
        asm volatile("s_waitcnt vmcnt(4)" ::: "memory");   // only k+2 remains
      } else {
        asm volatile("s_waitcnt vmcnt(0)" ::: "memory");   // last prefetch drained
      }
      __builtin_amdgcn_sched_barrier(0);
      __builtin_amdgcn_s_barrier();
      __builtin_amdgcn_sched_barrier(0);
    }
  }

  // ---- epilogue: C/D layout col=lane&15, row=quad*4+reg (verified m89/m91).
  // acc[i][j][r] -> token row = wm*128 + i*16 + quad*4 + r,
  //                col = col0 + wn*64 + j*16 + m_in.
  // Per-wave row partials -> LDS -> one atomicAdd per row per block.
  float* red = (float*)&As[0][0];  // 8 waves x 128 rows = 4 KB (buf0 dead)
  #pragma unroll
  for (int i = 0; i < 8; i++) {
    #pragma unroll
    for (int r = 0; r < 4; r++) {
      float s = 0.f;
      #pragma unroll
      for (int jj = 0; jj < 4; jj++) {
        int col = col0 + wn * 64 + jj * 16 + m_in;
        if (col < colEnd) s += __expf(acc[i][jj][r]);
      }
      s += __shfl_down(s, 8, 16);
      s += __shfl_down(s, 4, 16);
      s += __shfl_down(s, 2, 16);
      s += __shfl_down(s, 1, 16);
      if (m_in == 0) red[w * 128 + i * 16 + quad * 4 + r] = s;
    }
  }
  __syncthreads();
  if (tid < 256) {
    int row = tid, wm2 = row >> 7, rw = row & 127;
    float s = red[(wm2 * 4 + 0) * 128 + rw] + red[(wm2 * 4 + 1) * 128 + rw] +
              red[(wm2 * 4 + 2) * 128 + rw] + red[(wm2 * 4 + 3) * 128 + rw];
    if (t0 + row < tEnd) atomicAdd(&sumexp[t0 + row], s);
  }
}

// ---------------------------------------------------------------------------
// Kernel 6: finalize. sumexp is perm-indexed; scatter to token order.
// ---------------------------------------------------------------------------
__global__ __launch_bounds__(256) void final_kernel(
    const int* __restrict__ perm, const float* __restrict__ neg_cll,
    const float* __restrict__ z_tgt, const float* __restrict__ sumexp,
    float* __restrict__ out) {
  int p = blockIdx.x * 256 + threadIdx.x;
  if (p < NT) {
    int t = perm[p];
    out[t] = neg_cll[t] + logf(sumexp[p]) - z_tgt[t];
  }
}

// ===========================================================================
// Round-1 fp32 fallback path (used only if ws_size is too small for lt/xb).
// ===========================================================================
__global__ __launch_bounds__(256) void head_kernel_fb(
    const float* __restrict__ x, const int* __restrict__ y,
    const float* __restrict__ Wc, const float* __restrict__ logits,
    float* __restrict__ neg_cll, float* __restrict__ z_tgt) {
  int tid = threadIdx.x;
  int lane = tid & 63;
  int token = blockIdx.x * 4 + (tid >> 6);
  int yv = y[token];
  const float* xp = x + (size_t)token * H;
  float c0 = 0.f, c1 = 0.f, c2 = 0.f, zt = 0.f;
  #pragma unroll
  for (int j = 0; j < 16; j++) {
    int h = lane + j * 64;
    float xv = xp[h];
    c0 = fmaf(xv, Wc[h], c0);
    c1 = fmaf(xv, Wc[H + h], c1);
    c2 = fmaf(xv, Wc[2 * H + h], c2);
    zt = fmaf(xv, logits[(size_t)h * V + yv], zt);
  }
  #pragma unroll
  for (int d = 32; d; d >>= 1) {
    c0 += __shfl_down(c0, d);
    c1 += __shfl_down(c1, d);
    c2 += __shfl_down(c2, d);
    zt += __shfl_down(zt, d);
  }
  if (lane == 0) {
    float m = fmaxf(c0, fmaxf(c1, c2));
    float lse = m + logf(expf(c0 - m) + expf(c1 - m) + expf(c2 - m));
    int k = (yv >= CUT1) + (yv >= CUT2);
    float ck = (k == 0) ? c0 : ((k == 1) ? c1 : c2);
    neg_cll[token] = lse - ck;
    z_tgt[token] = zt;
  }
}

__global__ __launch_bounds__(256) void main_kernel_fb(
    const float* __restrict__ x, const float* __restrict__ logits,
    const int* __restrict__ offsets, const int* __restrict__ perm,
    float* __restrict__ sumexp) {
  int ct = blockIdx.x;
  int c, lct;
  if (ct < FB_TILES0)                  { c = 0; lct = ct; }
  else if (ct < FB_TILES0 + FB_TILES1) { c = 1; lct = ct - FB_TILES0; }
  else                                 { c = 2; lct = ct - FB_TILES0 - FB_TILES1; }
  int colBase = (c == 0) ? 0 : ((c == 1) ? CUT1 : CUT2);
  int colEnd  = (c == 0) ? CUT1 : ((c == 1) ? CUT2 : V);
  int col0 = colBase + lct * 64;
  int ncols = min(64, colEnd - col0);

  int t0 = offsets[c] + blockIdx.y * 64;
  int tEnd = offsets[c + 1];
  if (t0 >= tEnd) return;
  int ntok = min(64, tEnd - t0);

  __shared__ int tok_s[64];
  __shared__ float xsf[32][68];
  __shared__ float lsm[32][68];

  int tid = threadIdx.x;
  if (tid < 64) tok_s[tid] = perm[t0 + min(tid, ntok - 1)];
  __syncthreads();

  int tg = tid >> 4;
  int cg = tid & 15;
  float acc[4][4] = {};

  for (int h0 = 0; h0 < H; h0 += 32) {
    __syncthreads();
    #pragma unroll
    for (int e = 0; e < 8; e++) {
      int elem = e * 256 + tid;
      int tt = elem >> 5, kk = elem & 31;
      xsf[kk][tt] = x[(size_t)tok_s[tt] * H + h0 + kk];
    }
    #pragma unroll
    for (int e = 0; e < 8; e++) {
      int elem = e * 256 + tid;
      int kk = elem >> 6, cc = elem & 63;
      lsm[kk][cc] = (cc < ncols) ? logits[(size_t)(h0 + kk) * V + col0 + cc] : 0.f;
    }
    __syncthreads();
    #pragma unroll
    for (int kk = 0; kk < 32; kk++) {
      float4 xv = *(const float4*)&xsf[kk][4 * tg];
      float4 lv = *(const float4*)&lsm[kk][4 * cg];
      acc[0][0] = fmaf(xv.x, lv.x, acc[0][0]);
      acc[0][1] = fmaf(xv.x, lv.y, acc[0][1]);
      acc[0][2] = fmaf(xv.x, lv.z, acc[0][2]);
      acc[0][3] = fmaf(xv.x, lv.w, acc[0][3]);
      acc[1][0] = fmaf(xv.y, lv.x, acc[1][0]);
      acc[1][1] = fmaf(xv.y, lv.y, acc[1][1]);
      acc[1][2] = fmaf(xv.y, lv.z, acc[1][2]);
      acc[1][3] = fmaf(xv.y, lv.w, acc[1][3]);
      acc[2][0] = fmaf(xv.z, lv.x, acc[2][0]);
      acc[2][1] = fmaf(xv.z, lv.y, acc[2][1]);
      acc[2][2] = fmaf(xv.z, lv.z, acc[2][2]);
      acc[2][3] = fmaf(xv.z, lv.w, acc[2][3]);
      acc[3][0] = fmaf(xv.w, lv.x, acc[3][0]);
      acc[3][1] = fmaf(xv.w, lv.y, acc[3][1]);
      acc[3][2] = fmaf(xv.w, lv.z, acc[3][2]);
      acc[3][3] = fmaf(xv.w, lv.w, acc[3][3]);
    }
  }

  float s[4];
  #pragma unroll
  for (int i = 0; i < 4; i++) {
    float v = 0.f;
    #pragma unroll
    for (int j = 0; j < 4; j++) {
      if (4 * cg + j < ncols) v += expf(acc[i][j]);
    }
    s[i] = v;
  }
  #pragma unroll
  for (int i = 0; i < 4; i++) {
    #pragma unroll
    for (int d = 8; d; d >>= 1) s[i] += __shfl_down(s[i], d, 16);
  }
  if (cg == 0) {
    #pragma unroll
    for (int i = 0; i < 4; i++) {
      int tt = 4 * tg + i;
      if (tt < ntok) atomicAdd(&sumexp[tok_s[tt]], s[i]);
    }
  }
}

__global__ __launch_bounds__(256) void final_kernel_fb(
    const float* __restrict__ neg_cll, const float* __restrict__ z_tgt,
    const float* __restrict__ sumexp, float* __restrict__ out) {
  int i = blockIdx.x * 256 + threadIdx.x;
  if (i < NT) out[i] = neg_cll[i] + logf(sumexp[i]) - z_tgt[i];
}

// ===========================================================================
extern "C" void kernel_launch(void* const* d_in, const int* in_sizes, int n_in,
                              void* d_out, int out_size, void* d_ws,
                              size_t ws_size, hipStream_t stream) {
  const float* x      = (const float*)d_in[0];
  const int*   y      = (const int*)d_in[1];
  const float* Wc     = (const float*)d_in[2];
  const float* logits = (const float*)d_in[3];
  float* out = (float*)d_out;

  char* ws = (char*)d_ws;
  int*   offsets = (int*)ws;                      // @0, 16 B
  int*   perm    = (int*)(ws + 256);              // 16 KB
  float* sumexp  = (float*)(ws + 16896);          // 16 KB (perm-order)
  float* neg_cll = (float*)(ws + 33280);          // 16 KB
  float* z_tgt   = (float*)(ws + 49664);          // 16 KB
  ushort_t* xb   = (ushort_t*)(ws + 66048);       // 4352*1024*2 B
  ushort_t* lt   = (ushort_t*)(ws + 66048 + (size_t)NPAD_TOK * H * 2);
  const size_t WS_NEED = 66048 + (size_t)NPAD_TOK * H * 2 + (size_t)NPAD_COL * H * 2;

  setup_kernel<<<1, 1024, 0, stream>>>(y, offsets, perm, sumexp);

  if (ws_size >= WS_NEED) {
    gather_kernel<<<NPAD_TOK, 256, 0, stream>>>(x, perm, xb);
    dim3 tg(NPAD_COL / 128, H / 64);
    transpose_kernel<<<tg, 256, 0, stream>>>(logits, lt);
    head_kernel<<<NT / 4, 256, 0, stream>>>(x, y, Wc, lt, neg_cll, z_tgt);
    mfma_kernel<<<MFMA_GRID, 512, 0, stream>>>(xb, lt, offsets, sumexp);
    final_kernel<<<NT / 256, 256, 0, stream>>>(perm, neg_cll, z_tgt, sumexp, out);
  } else {
    head_kernel_fb<<<NT / 4, 256, 0, stream>>>(x, y, Wc, logits, neg_cll, z_tgt);
    dim3 grid(FB_TOTAL, 64);
    main_kernel_fb<<<grid, 256, 0, stream>>>(x, logits, offsets, perm, sumexp);
    final_kernel_fb<<<NT / 256, 256, 0, stream>>>(neg_cll, z_tgt, sumexp, out);
  }
}

// Round 4
// 524.237 us; speedup vs baseline: 1.1117x; 1.1117x over previous
//
#include <hip/hip_runtime.h>
#include <math.h>

typedef unsigned short ushort_t;
typedef __attribute__((ext_vector_type(8))) short short8;   // 8 bf16 = 4 VGPRs
typedef __attribute__((ext_vector_type(4))) float floatx4;  // MFMA accumulator

// Problem constants
constexpr int NT = 4096;     // tokens
constexpr int H  = 1024;     // hidden
constexpr int V  = 50257;    // vocab
constexpr int CUT1 = 20000;
constexpr int CUT2 = 40000;

// MFMA-path geometry (256x256 tile, BK=64, 8-phase schedule)
constexpr int NPAD_TOK = 4352;            // 4096 + 256 pad rows (zeroed)
constexpr int NPAD_COL = 50560;           // covers 50240+256
constexpr int CT0 = 79, CT1 = 79, CT2 = 41;    // 256-wide col tiles
constexpr int CT_TOTAL = CT0 + CT1 + CT2;      // 199
constexpr int MAX_TTILES = 16;                 // 4096/256 worst case
constexpr int CT_GROUPS = (CT_TOTAL + 7) / 8;  // 25 per XCD
constexpr int MFMA_GRID = 8 * CT_GROUPS * MAX_TTILES;  // 3200 blocks
constexpr int NKT = H / 64;                    // 16 K-steps of BK=64

// fp32 fallback geometry (round-1 path, used only if ws too small)
constexpr int FB_TILES0 = (20000 + 63) / 64;
constexpr int FB_TILES1 = (20000 + 63) / 64;
constexpr int FB_TILES2 = (V - 40000 + 63) / 64;
constexpr int FB_TOTAL = FB_TILES0 + FB_TILES1 + FB_TILES2;

__device__ __forceinline__ ushort_t f2bf(float f) {
  unsigned int u = __float_as_uint(f);
  u = (u + 0x7FFFu + ((u >> 16) & 1u)) >> 16;  // round-to-nearest-even
  return (ushort_t)u;
}
__device__ __forceinline__ float bf2f(ushort_t b) {
  return __uint_as_float(((unsigned int)b) << 16);
}
__device__ __forceinline__ void gl_lds16(const void* g, void* l) {
  __builtin_amdgcn_global_load_lds(
      (const __attribute__((address_space(1))) void*)g,
      (__attribute__((address_space(3))) void*)l, 16, 0, 0);
}

// ---------------------------------------------------------------------------
// Kernel 1: classify tokens, build perm (ballot + exact prefix, atomic-free,
// deterministic), zero sumexp.
// ---------------------------------------------------------------------------
__global__ __launch_bounds__(1024) void setup_kernel(
    const int* __restrict__ y, int* __restrict__ offsets,
    int* __restrict__ perm, float* __restrict__ sumexp) {
  __shared__ int wcnt[16][3];
  __shared__ int wstart[16][3];
  int tid = threadIdx.x, lane = tid & 63, wid = tid >> 6;
  for (int i = tid; i < NT; i += 1024) sumexp[i] = 0.f;

  int kc[4];
  unsigned long long msk[4][3];
  int cw0 = 0, cw1 = 0, cw2 = 0;
  #pragma unroll
  for (int e = 0; e < 4; e++) {
    int v = y[tid + e * 1024];
    kc[e] = (v >= CUT1) + (v >= CUT2);
    msk[e][0] = __ballot(kc[e] == 0);
    msk[e][1] = __ballot(kc[e] == 1);
    msk[e][2] = __ballot(kc[e] == 2);
    cw0 += __popcll(msk[e][0]);
    cw1 += __popcll(msk[e][1]);
    cw2 += __popcll(msk[e][2]);
  }
  if (lane == 0) { wcnt[wid][0] = cw0; wcnt[wid][1] = cw1; wcnt[wid][2] = cw2; }
  __syncthreads();
  if (tid == 0) {
    int t0 = 0, t1 = 0, t2 = 0;
    for (int wv = 0; wv < 16; wv++) { t0 += wcnt[wv][0]; t1 += wcnt[wv][1]; t2 += wcnt[wv][2]; }
    offsets[0] = 0; offsets[1] = t0; offsets[2] = t0 + t1; offsets[3] = NT;
    int c0 = 0, c1 = t0, c2 = t0 + t1;
    for (int wv = 0; wv < 16; wv++) {
      wstart[wv][0] = c0; c0 += wcnt[wv][0];
      wstart[wv][1] = c1; c1 += wcnt[wv][1];
      wstart[wv][2] = c2; c2 += wcnt[wv][2];
    }
  }
  __syncthreads();
  int r0 = wstart[wid][0], r1 = wstart[wid][1], r2 = wstart[wid][2];
  unsigned long long below = (1ull << lane) - 1ull;
  #pragma unroll
  for (int e = 0; e < 4; e++) {
    int t = tid + e * 1024;
    int c = kc[e];
    int start = (c == 0) ? r0 : ((c == 1) ? r1 : r2);
    perm[start + __popcll(msk[e][c] & below)] = t;
    r0 += __popcll(msk[e][0]);
    r1 += __popcll(msk[e][1]);
    r2 += __popcll(msk[e][2]);
  }
}

// ---------------------------------------------------------------------------
// Kernel 2: gather x into perm order as bf16 (float4 -> ushort4); zero pad.
// ---------------------------------------------------------------------------
__global__ __launch_bounds__(256) void gather_kernel(
    const float* __restrict__ x, const int* __restrict__ perm,
    ushort_t* __restrict__ xb) {
  int p = blockIdx.x;
  int src = (p < NT) ? perm[p] : -1;
  int k = threadIdx.x * 4;
  ushort4 o;
  if (src >= 0) {
    float4 v = *(const float4*)&x[(size_t)src * H + k];
    o.x = f2bf(v.x); o.y = f2bf(v.y); o.z = f2bf(v.z); o.w = f2bf(v.w);
  } else {
    o.x = 0; o.y = 0; o.z = 0; o.w = 0;
  }
  *(ushort4*)&xb[(size_t)p * H + k] = o;
}

// ---------------------------------------------------------------------------
// Kernel 3: transpose+convert logits [H][V] fp32 -> lt [NPAD_COL][H] bf16.
// ---------------------------------------------------------------------------
__global__ __launch_bounds__(256) void transpose_kernel(
    const float* __restrict__ logits, ushort_t* __restrict__ lt) {
  __shared__ float ts[64][129];
  int col0 = blockIdx.x * 128, k0 = blockIdx.y * 64;
  int tid = threadIdx.x;
  #pragma unroll
  for (int e = 0; e < 8; e++) {
    int i = e * 256 + tid;       // 0..2047
    int r = i >> 5, q = i & 31;  // row 0..63, float4-slot 0..31
    int col = col0 + q * 4;
    float4 v;
    if (col + 3 < V) {
      v = *(const float4*)&logits[(size_t)(k0 + r) * V + col];
    } else {
      v.x = (col + 0 < V) ? logits[(size_t)(k0 + r) * V + col + 0] : 0.f;
      v.y = (col + 1 < V) ? logits[(size_t)(k0 + r) * V + col + 1] : 0.f;
      v.z = (col + 2 < V) ? logits[(size_t)(k0 + r) * V + col + 2] : 0.f;
      v.w = (col + 3 < V) ? logits[(size_t)(k0 + r) * V + col + 3] : 0.f;
    }
    ts[r][4 * q + 0] = v.x;
    ts[r][4 * q + 1] = v.y;
    ts[r][4 * q + 2] = v.z;
    ts[r][4 * q + 3] = v.w;
  }
  __syncthreads();
  #pragma unroll
  for (int e = 0; e < 4; e++) {
    int i = e * 256 + tid;          // 0..1023
    int col = i >> 3, kq8 = i & 7;  // col 0..127, 8-k group 0..7
    short8 o;
    #pragma unroll
    for (int d = 0; d < 8; d++) o[d] = (short)f2bf(ts[8 * kq8 + d][col]);
    *(short8*)&lt[(size_t)(col0 + col) * H + k0 + 8 * kq8] = o;
  }
}

// ---------------------------------------------------------------------------
// Kernel 4: cluster-head log-softmax (fp32) + target logit (bf16 lt row).
// ---------------------------------------------------------------------------
__global__ __launch_bounds__(256) void head_kernel(
    const float* __restrict__ x, const int* __restrict__ y,
    const float* __restrict__ Wc, const ushort_t* __restrict__ lt,
    float* __restrict__ neg_cll, float* __restrict__ z_tgt) {
  int tid = threadIdx.x;
  int lane = tid & 63;
  int token = blockIdx.x * 4 + (tid >> 6);
  int yv = y[token];
  const float* xp = x + (size_t)token * H;
  const ushort_t* lp = lt + (size_t)yv * H;
  float c0 = 0.f, c1 = 0.f, c2 = 0.f, zt = 0.f;
  #pragma unroll
  for (int j = 0; j < 16; j++) {
    int h = lane + j * 64;
    float xv = xp[h];
    c0 = fmaf(xv, Wc[h], c0);
    c1 = fmaf(xv, Wc[H + h], c1);
    c2 = fmaf(xv, Wc[2 * H + h], c2);
    zt = fmaf(xv, bf2f(lp[h]), zt);
  }
  #pragma unroll
  for (int d = 32; d; d >>= 1) {
    c0 += __shfl_down(c0, d);
    c1 += __shfl_down(c1, d);
    c2 += __shfl_down(c2, d);
    zt += __shfl_down(zt, d);
  }
  if (lane == 0) {
    float m = fmaxf(c0, fmaxf(c1, c2));
    float lse = m + logf(expf(c0 - m) + expf(c1 - m) + expf(c2 - m));
    int k = (yv >= CUT1) + (yv >= CUT2);
    float ck = (k == 0) ? c0 : ((k == 1) ? c1 : c2);
    neg_cll[token] = lse - ck;
    z_tgt[token] = zt;
  }
}

// ---------------------------------------------------------------------------
// Kernel 5: MFMA main loop — 256x256 tile, BK=64, 8-PHASE schedule (T2+T3+
// T4+T5 per m201). 512 threads = 8 waves (2M x 4N), per-wave output 128x64.
// Per K-step: 4 phases, each = {ds_read subtile (12 at p1, 4 at p2-4) ||
// stage ONE half-tile (2 gl_lds) -> barrier -> lgkmcnt(0) -> 16 MFMA
// (setprio) -> barrier}. Counted vmcnt(4) ONCE per K-step at the phase-4
// closing barrier (2 half-tiles = B(n+2) stay in flight, FIFO retirement
// guarantees K-step n+1's 4 half-tiles landed). Stage stream: A(n+1) at
// phases 1-2 into the idle dbuf; B(n+2) at phases 3-4 into the current
// dbuf's B regions (B frags are consumed entirely at phase 1, so those
// regions are dead by phase 3 -- write-issue is barrier-ordered after all
// waves' phase-1 lgkmcnt(0)). Rationale: r1/r3 both pinned at 985 FLOP/cy/CU
// (25% MfmaUtil) -- coarse lockstep phases sum instead of overlap (m233);
// the fine interleave is the proven lever (m196/m218: +28-73%).
// LDS swizzle: slot=(h*4+quad)^(row&7), inverse-swizzled global source
// (q=(lane&7)^(lane>>3)) -- exact 2-way read aliasing = free, verified 0
// conflicts in r1/r3 with the same involution discipline.
// ---------------------------------------------------------------------------
__global__ __launch_bounds__(512, 2) void mfma_kernel(
    const ushort_t* __restrict__ xb, const ushort_t* __restrict__ lt,
    const int* __restrict__ offsets, float* __restrict__ sumexp) {
  // XCD-aware decode: xcd = id%8 handles cts {xcd, xcd+8, ...}
  int id = blockIdx.x;
  int xcd = id & 7;
  int j = id >> 3;
  int ct = xcd + 8 * (j >> 4);   // ct-group per XCD
  int tt = j & 15;               // token tile within ct
  if (ct >= CT_TOTAL) return;

  int c_cl, col0, colEnd;
  if (ct < CT0)            { c_cl = 0; col0 = ct * 256;                      colEnd = CUT1; }
  else if (ct < CT0 + CT1) { c_cl = 1; col0 = CUT1 + (ct - CT0) * 256;       colEnd = CUT2; }
  else                     { c_cl = 2; col0 = CUT2 + (ct - CT0 - CT1) * 256; colEnd = V; }

  int t0 = offsets[c_cl] + tt * 256;
  int tEnd = offsets[c_cl + 1];
  if (t0 >= tEnd) return;  // uniform across block: no barrier divergence

  // 2 dbuf x (A 256x64 + B 256x64) bf16 = 128 KB LDS
  __shared__ __align__(16) ushort_t As[2][256 * 64];
  __shared__ __align__(16) ushort_t Bs[2][256 * 64];

  int tid = threadIdx.x;
  int lane = tid & 63;
  int w = tid >> 6;                 // wave 0..7
  int wm = w >> 2, wn = w & 3;      // 2x4 wave grid
  int m_in = lane & 15, quad = lane >> 4;

  // ---- staging source map (pre-swizzled global, linear LDS dst):
  // gl_lds dst = base + lane*16 -> LDS row = rowbase + (lane>>3), slot = lane&7.
  // Reader expects chunk (slot ^ (row&7)) at slot -> source chunk:
  int qsw  = (lane & 7) ^ (lane >> 3);
  int rofs = lane >> 3;
  const ushort_t* pA[2];
  const ushort_t* pB[2];
  #pragma unroll
  for (int cc = 0; cc < 2; cc++) {
    pA[cc] = xb + (size_t)(t0 + w * 16 + cc * 8 + rofs) * H + qsw * 8;
    pB[cc] = lt + (size_t)(col0 + w * 16 + cc * 8 + rofs) * H + qsw * 8;
  }
  auto STAGE_A = [&](int cA, int hi) {
    #pragma unroll
    for (int cc = 0; cc < 2; cc++)
      gl_lds16(pA[cc] + (size_t)hi * 128 * H,
               &As[cA][(hi * 128 + w * 16 + cc * 8) * 64]);
  };
  auto STAGE_B = [&](int cB, int hi) {
    #pragma unroll
    for (int cc = 0; cc < 2; cc++)
      gl_lds16(pB[cc] + (size_t)hi * 128 * H,
               &Bs[cB][(hi * 128 + w * 16 + cc * 8) * 64]);
  };

  // ---- read-side addressing: row r, k-chunk (h*4+quad) at slot
  // (h*4+quad)^(r&7); r&7 == m_in&7 for all fragment rows.
  int sx0 = quad ^ (m_in & 7);        // h=0
  int sx1 = (4 + quad) ^ (m_in & 7);  // h=1
  int rbaseA = wm * 128 + m_in;
  int rbaseB = wn * 64 + m_in;

  floatx4 acc[8][4];
  #pragma unroll
  for (int i = 0; i < 8; i++)
    #pragma unroll
    for (int jj = 0; jj < 4; jj++)
      acc[i][jj] = (floatx4){0.f, 0.f, 0.f, 0.f};

  short8 af[2][2];   // A frags: [row-frag][k-half], per phase
  short8 bfr[4][2];  // B frags: [col-frag][k-half], per K-step

#define LDA_PHASE(Q)                                                          \
  do {                                                                        \
    _Pragma("unroll") for (int ii = 0; ii < 2; ii++) {                        \
      af[ii][0] = *(const short8*)&Ac[(rbaseA + (Q)*32 + ii*16)*64 + sx0*8];  \
      af[ii][1] = *(const short8*)&Ac[(rbaseA + (Q)*32 + ii*16)*64 + sx1*8];  \
    }                                                                         \
  } while (0)

#define MM_PHASE(Q)                                                           \
  do {                                                                        \
    __builtin_amdgcn_s_setprio(1);                                            \
    _Pragma("unroll") for (int ii = 0; ii < 2; ii++)                          \
      _Pragma("unroll") for (int jj = 0; jj < 4; jj++) {                      \
        acc[2*(Q)+ii][jj] = __builtin_amdgcn_mfma_f32_16x16x32_bf16(          \
            af[ii][0], bfr[jj][0], acc[2*(Q)+ii][jj], 0, 0, 0);               \
        acc[2*(Q)+ii][jj] = __builtin_amdgcn_mfma_f32_16x16x32_bf16(          \
            af[ii][1], bfr[jj][1], acc[2*(Q)+ii][jj], 0, 0, 0);               \
      }                                                                       \
    __builtin_amdgcn_s_setprio(0);                                            \
  } while (0)

#define WAIT_LGKM0                                                            \
  asm volatile("s_waitcnt lgkmcnt(0)" ::: "memory");                          \
  __builtin_amdgcn_sched_barrier(0)

#define BAR                                                                   \
  __builtin_amdgcn_sched_barrier(0);                                          \
  __builtin_amdgcn_s_barrier();                                               \
  __builtin_amdgcn_sched_barrier(0)

  // ---- prologue: stage B(0), A(0) -> dbuf0; B(1) -> dbuf1.  12 loads;
  // vmcnt(4): K-step 0's 8 oldest landed, B(1)'s 4 in flight.
  STAGE_B(0, 0); STAGE_B(0, 1); pB[0] += 64; pB[1] += 64;
  STAGE_A(0, 0); STAGE_A(0, 1); pA[0] += 64; pA[1] += 64;
  STAGE_B(1, 0); STAGE_B(1, 1); pB[0] += 64; pB[1] += 64;
  asm volatile("s_waitcnt vmcnt(4)" ::: "memory");
  BAR;

  // ---- main loop: NKT K-steps x 4 phases; one counted vmcnt per K-step.
  #pragma unroll 2
  for (int n = 0; n < NKT; ++n) {
    int c = n & 1;
    const ushort_t* Ac = &As[c][0];
    const ushort_t* Bc = &Bs[c][0];
    bool stA = (n + 1 < NKT);
    bool stB = (n + 2 < NKT);

    // ---- phase 1: read all B (8) + A q0 (4); stage A-lo(n+1) -> dbuf c^1
    #pragma unroll
    for (int jj = 0; jj < 4; jj++) {
      bfr[jj][0] = *(const short8*)&Bc[(rbaseB + jj * 16) * 64 + sx0 * 8];
      bfr[jj][1] = *(const short8*)&Bc[(rbaseB + jj * 16) * 64 + sx1 * 8];
    }
    LDA_PHASE(0);
    if (stA) STAGE_A(c ^ 1, 0);
    asm volatile("s_waitcnt lgkmcnt(8)" ::: "memory");
    BAR;
    WAIT_LGKM0;
    MM_PHASE(0);
    BAR;

    // ---- phase 2: A q1; stage A-hi(n+1)
    LDA_PHASE(1);
    if (stA) { STAGE_A(c ^ 1, 1); pA[0] += 64; pA[1] += 64; }
    BAR;
    WAIT_LGKM0;
    MM_PHASE(1);
    BAR;

    // ---- phase 3: A q2; stage B-lo(n+2) -> dbuf c (B-lo dead since p1)
    LDA_PHASE(2);
    if (stB) STAGE_B(c, 0);
    BAR;
    WAIT_LGKM0;
    MM_PHASE(2);
    BAR;

    // ---- phase 4: A q3; stage B-hi(n+2); K-step boundary (counted vmcnt)
    LDA_PHASE(3);
    if (stB) { STAGE_B(c, 1); pB[0] += 64; pB[1] += 64; }
    BAR;
    WAIT_LGKM0;
    MM_PHASE(3);
    __builtin_amdgcn_sched_barrier(0);
    if (n < NKT - 2) {
      asm volatile("s_waitcnt vmcnt(4)" ::: "memory");  // B(n+2) in flight
    } else if (n == NKT - 2) {
      asm volatile("s_waitcnt vmcnt(0)" ::: "memory");  // drain last prefetch
    }
    BAR;
  }
#undef LDA_PHASE
#undef MM_PHASE
#undef WAIT_LGKM0
#undef BAR

  // ---- epilogue: C/D layout col=lane&15, row=quad*4+reg (verified m89/m91).
  // acc[i][j][r] -> token row = wm*128 + i*16 + quad*4 + r,
  //                col = col0 + wn*64 + j*16 + m_in.
  // Per-wave row partials -> LDS -> one atomicAdd per row per block.
  __syncthreads();
  float* red = (float*)&As[0][0];  // 8 waves x 128 rows = 4 KB
  #pragma unroll
  for (int i = 0; i < 8; i++) {
    #pragma unroll
    for (int r = 0; r < 4; r++) {
      float s = 0.f;
      #pragma unroll
      for (int jj = 0; jj < 4; jj++) {
        int col = col0 + wn * 64 + jj * 16 + m_in;
        if (col < colEnd) s += __expf(acc[i][jj][r]);
      }
      s += __shfl_down(s, 8, 16);
      s += __shfl_down(s, 4, 16);
      s += __shfl_down(s, 2, 16);
      s += __shfl_down(s, 1, 16);
      if (m_in == 0) red[w * 128 + i * 16 + quad * 4 + r] = s;
    }
  }
  __syncthreads();
  if (tid < 256) {
    int row = tid, wm2 = row >> 7, rw = row & 127;
    float s = red[(wm2 * 4 + 0) * 128 + rw] + red[(wm2 * 4 + 1) * 128 + rw] +
              red[(wm2 * 4 + 2) * 128 + rw] + red[(wm2 * 4 + 3) * 128 + rw];
    if (t0 + row < tEnd) atomicAdd(&sumexp[t0 + row], s);
  }
}

// ---------------------------------------------------------------------------
// Kernel 6: finalize. sumexp is perm-indexed; scatter to token order.
// ---------------------------------------------------------------------------
__global__ __launch_bounds__(256) void final_kernel(
    const int* __restrict__ perm, const float* __restrict__ neg_cll,
    const float* __restrict__ z_tgt, const float* __restrict__ sumexp,
    float* __restrict__ out) {
  int p = blockIdx.x * 256 + threadIdx.x;
  if (p < NT) {
    int t = perm[p];
    out[t] = neg_cll[t] + logf(sumexp[p]) - z_tgt[t];
  }
}

// ===========================================================================
// Round-1 fp32 fallback path (used only if ws_size is too small for lt/xb).
// ===========================================================================
__global__ __launch_bounds__(256) void head_kernel_fb(
    const float* __restrict__ x, const int* __restrict__ y,
    const float* __restrict__ Wc, const float* __restrict__ logits,
    float* __restrict__ neg_cll, float* __restrict__ z_tgt) {
  int tid = threadIdx.x;
  int lane = tid & 63;
  int token = blockIdx.x * 4 + (tid >> 6);
  int yv = y[token];
  const float* xp = x + (size_t)token * H;
  float c0 = 0.f, c1 = 0.f, c2 = 0.f, zt = 0.f;
  #pragma unroll
  for (int j = 0; j < 16; j++) {
    int h = lane + j * 64;
    float xv = xp[h];
    c0 = fmaf(xv, Wc[h], c0);
    c1 = fmaf(xv, Wc[H + h], c1);
    c2 = fmaf(xv, Wc[2 * H + h], c2);
    zt = fmaf(xv, logits[(size_t)h * V + yv], zt);
  }
  #pragma unroll
  for (int d = 32; d; d >>= 1) {
    c0 += __shfl_down(c0, d);
    c1 += __shfl_down(c1, d);
    c2 += __shfl_down(c2, d);
    zt += __shfl_down(zt, d);
  }
  if (lane == 0) {
    float m = fmaxf(c0, fmaxf(c1, c2));
    float lse = m + logf(expf(c0 - m) + expf(c1 - m) + expf(c2 - m));
    int k = (yv >= CUT1) + (yv >= CUT2);
    float ck = (k == 0) ? c0 : ((k == 1) ? c1 : c2);
    neg_cll[token] = lse - ck;
    z_tgt[token] = zt;
  }
}

__global__ __launch_bounds__(256) void main_kernel_fb(
    const float* __restrict__ x, const float* __restrict__ logits,
    const int* __restrict__ offsets, const int* __restrict__ perm,
    float* __restrict__ sumexp) {
  int ct = blockIdx.x;
  int c, lct;
  if (ct < FB_TILES0)                  { c = 0; lct = ct; }
  else if (ct < FB_TILES0 + FB_TILES1) { c = 1; lct = ct - FB_TILES0; }
  else                                 { c = 2; lct = ct - FB_TILES0 - FB_TILES1; }
  int colBase = (c == 0) ? 0 : ((c == 1) ? CUT1 : CUT2);
  int colEnd  = (c == 0) ? CUT1 : ((c == 1) ? CUT2 : V);
  int col0 = colBase + lct * 64;
  int ncols = min(64, colEnd - col0);

  int t0 = offsets[c] + blockIdx.y * 64;
  int tEnd = offsets[c + 1];
  if (t0 >= tEnd) return;
  int ntok = min(64, tEnd - t0);

  __shared__ int tok_s[64];
  __shared__ float xsf[32][68];
  __shared__ float lsm[32][68];

  int tid = threadIdx.x;
  if (tid < 64) tok_s[tid] = perm[t0 + min(tid, ntok - 1)];
  __syncthreads();

  int tg = tid >> 4;
  int cg = tid & 15;
  float acc[4][4] = {};

  for (int h0 = 0; h0 < H; h0 += 32) {
    __syncthreads();
    #pragma unroll
    for (int e = 0; e < 8; e++) {
      int elem = e * 256 + tid;
      int tt = elem >> 5, kk = elem & 31;
      xsf[kk][tt] = x[(size_t)tok_s[tt] * H + h0 + kk];
    }
    #pragma unroll
    for (int e = 0; e < 8; e++) {
      int elem = e * 256 + tid;
      int kk = elem >> 6, cc = elem & 63;
      lsm[kk][cc] = (cc < ncols) ? logits[(size_t)(h0 + kk) * V + col0 + cc] : 0.f;
    }
    __syncthreads();
    #pragma unroll
    for (int kk = 0; kk < 32; kk++) {
      float4 xv = *(const float4*)&xsf[kk][4 * tg];
      float4 lv = *(const float4*)&lsm[kk][4 * cg];
      acc[0][0] = fmaf(xv.x, lv.x, acc[0][0]);
      acc[0][1] = fmaf(xv.x, lv.y, acc[0][1]);
      acc[0][2] = fmaf(xv.x, lv.z, acc[0][2]);
      acc[0][3] = fmaf(xv.x, lv.w, acc[0][3]);
      acc[1][0] = fmaf(xv.y, lv.x, acc[1][0]);
      acc[1][1] = fmaf(xv.y, lv.y, acc[1][1]);
      acc[1][2] = fmaf(xv.y, lv.z, acc[1][2]);
      acc[1][3] = fmaf(xv.y, lv.w, acc[1][3]);
      acc[2][0] = fmaf(xv.z, lv.x, acc[2][0]);
      acc[2][1] = fmaf(xv.z, lv.y, acc[2][1]);
      acc[2][2] = fmaf(xv.z, lv.z, acc[2][2]);
      acc[2][3] = fmaf(xv.z, lv.w, acc[2][3]);
      acc[3][0] = fmaf(xv.w, lv.x, acc[3][0]);
      acc[3][1] = fmaf(xv.w, lv.y, acc[3][1]);
      acc[3][2] = fmaf(xv.w, lv.z, acc[3][2]);
      acc[3][3] = fmaf(xv.w, lv.w, acc[3][3]);
    }
  }

  float s[4];
  #pragma unroll
  for (int i = 0; i < 4; i++) {
    float v = 0.f;
    #pragma unroll
    for (int j = 0; j < 4; j++) {
      if (4 * cg + j < ncols) v += expf(acc[i][j]);
    }
    s[i] = v;
  }
  #pragma unroll
  for (int i = 0; i < 4; i++) {
    #pragma unroll
    for (int d = 8; d; d >>= 1) s[i] += __shfl_down(s[i], d, 16);
  }
  if (cg == 0) {
    #pragma unroll
    for (int i = 0; i < 4; i++) {
      int tt = 4 * tg + i;
      if (tt < ntok) atomicAdd(&sumexp[tok_s[tt]], s[i]);
    }
  }
}

__global__ __launch_bounds__(256) void final_kernel_fb(
    const float* __restrict__ neg_cll, const float* __restrict__ z_tgt,
    const float* __restrict__ sumexp, float* __restrict__ out) {
  int i = blockIdx.x * 256 + threadIdx.x;
  if (i < NT) out[i] = neg_cll[i] + logf(sumexp[i]) - z_tgt[i];
}

// ===========================================================================
extern "C" void kernel_launch(void* const* d_in, const int* in_sizes, int n_in,
                              void* d_out, int out_size, void* d_ws,
                              size_t ws_size, hipStream_t stream) {
  const float* x      = (const float*)d_in[0];
  const int*   y      = (const int*)d_in[1];
  const float* Wc     = (const float*)d_in[2];
  const float* logits = (const float*)d_in[3];
  float* out = (float*)d_out;

  char* ws = (char*)d_ws;
  int*   offsets = (int*)ws;                      // @0, 16 B
  int*   perm    = (int*)(ws + 256);              // 16 KB
  float* sumexp  = (float*)(ws + 16896);          // 16 KB (perm-order)
  float* neg_cll = (float*)(ws + 33280);          // 16 KB
  float* z_tgt   = (float*)(ws + 49664);          // 16 KB
  ushort_t* xb   = (ushort_t*)(ws + 66048);       // 4352*1024*2 B
  ushort_t* lt   = (ushort_t*)(ws + 66048 + (size_t)NPAD_TOK * H * 2);
  const size_t WS_NEED = 66048 + (size_t)NPAD_TOK * H * 2 + (size_t)NPAD_COL * H * 2;

  setup_kernel<<<1, 1024, 0, stream>>>(y, offsets, perm, sumexp);

  if (ws_size >= WS_NEED) {
    gather_kernel<<<NPAD_TOK, 256, 0, stream>>>(x, perm, xb);
    dim3 tg(NPAD_COL / 128, H / 64);
    transpose_kernel<<<tg, 256, 0, stream>>>(logits, lt);
    head_kernel<<<NT / 4, 256, 0, stream>>>(x, y, Wc, lt, neg_cll, z_tgt);
    mfma_kernel<<<MFMA_GRID, 512, 0, stream>>>(xb, lt, offsets, sumexp);
    final_kernel<<<NT / 256, 256, 0, stream>>>(perm, neg_cll, z_tgt, sumexp, out);
  } else {
    head_kernel_fb<<<NT / 4, 256, 0, stream>>>(x, y, Wc, logits, neg_cll, z_tgt);
    dim3 grid(FB_TOTAL, 64);
    main_kernel_fb<<<grid, 256, 0, stream>>>(x, logits, offsets, perm, sumexp);
    final_kernel_fb<<<NT / 256, 256, 0, stream>>>(neg_cll, z_tgt, sumexp, out);
  }
}